// Round 11
// baseline (268.037 us; speedup 1.0000x reference)
//
#include <hip/hip_runtime.h>
#include <stdint.h>

typedef _Float16 f16;
typedef _Float16 f16x4 __attribute__((ext_vector_type(4)));
typedef _Float16 f16x8 __attribute__((ext_vector_type(8)));
typedef float f32x4 __attribute__((ext_vector_type(4)));

#define K_DIM 1600
#define NF_DIM 6400
#define KPAD 1664        // 26 tiles of 64
#define NKT 26
#define KB52 52          // KPAD/32 k-blocks
#define KPB (KPAD * 2)   // wqt row stride bytes = 3328

// GEMM: BM=128, BN=320, BK=64 -> 1280 tiles = 5/CU exact. 8 waves (2m x 4n),
// wave tile 64x80. A read direct from fragment-tiled qxt (no LDS); B via LDS.
#define BUFB 40960       // one B buffer: 320x64 f16

// ---------- async global->LDS 16B copy ----------
__device__ __forceinline__ void async_copy16(const void* g, void* l) {
    __builtin_amdgcn_global_load_lds(
        (const __attribute__((address_space(1))) void*)(uintptr_t)g,
        (__attribute__((address_space(3))) void*)(uint32_t)(uintptr_t)l,
        16, 0, 0);
}

// ---------- block-wide max (256 threads = 4 waves) ----------
__device__ __forceinline__ float blockMax(float v, float* sm) {
#pragma unroll
    for (int off = 32; off > 0; off >>= 1)
        v = fmaxf(v, __shfl_down(v, off, 64));
    int wid = threadIdx.x >> 6, lane = threadIdx.x & 63;
    if (lane == 0) sm[wid] = v;
    __syncthreads();
    if (threadIdx.x == 0) {
        float m = sm[0];
        for (int i = 1; i < (int)(blockDim.x >> 6); ++i) m = fmaxf(m, sm[i]);
        sm[0] = m;
    }
    __syncthreads();
    return sm[0];
}

// ---------- activation quant -> fragment-tiled qxt + ax ----------
// qxt chunk layout: ((mb*52 + kb)*64 + lane)*8 f16, lane = lg*16+lr holds
// rows mb*16+lr, k = kb*32+lg*8 .. +7.  16 rows per block, LDS-bounced.
#define QSTRIDE 1604     // padded f32 row stride (401 float4)
__global__ void quant_x_kernel(const float* __restrict__ x, f16* __restrict__ qxt,
                               float* __restrict__ ax) {
    extern __shared__ float xs[];   // [16][1604]
    __shared__ float sm[16];
    const int mb = blockIdx.x;      // 0..511
    const int tid = threadIdx.x;
    const float4* xb4 = (const float4*)(x + (size_t)mb * 16 * K_DIM);
    float4* xs4 = (float4*)xs;
    // load 16x1600 coalesced into padded LDS
#pragma unroll
    for (int rr = 0; rr < 16; ++rr)
        for (int i = tid; i < 400; i += 256)
            xs4[rr * 401 + i] = xb4[rr * 400 + i];
    __syncthreads();
    // per-row max: 16 threads per row (within-wave 16-groups)
    {
        int r = tid >> 4, si = tid & 15;
        float m = 0.f;
        const float4* row4 = (const float4*)(xs + r * QSTRIDE);
        for (int j = si; j < 400; j += 16) {
            float4 v = row4[j];
            m = fmaxf(fmaxf(fmaxf(fabsf(v.x), fabsf(v.y)), fmaxf(fabsf(v.z), fabsf(v.w))), m);
        }
#pragma unroll
        for (int o = 8; o > 0; o >>= 1) m = fmaxf(m, __shfl_xor(m, o, 64));
        if (si == 0) sm[r] = m;
    }
    __syncthreads();
    if (tid < 16) {
        float s = 127.0f / (sm[tid] + 1e-6f);
        ax[mb * 16 + tid] = 1.0f / (s + 1e-6f);
        sm[tid] = s;
    }
    __syncthreads();
    // write tiled chunks: 52 kb x 64 lanes; coalesced 16B stores
    f16* outb = qxt + (size_t)mb * KB52 * 512;
    for (int c = tid; c < KB52 * 64; c += 256) {
        int kb = c >> 6, lane = c & 63;
        int lr = lane & 15, lg = lane >> 4;
        int k0 = kb * 32 + lg * 8;
        f16x8 q = {};
        if (k0 < K_DIM) {
            float s = sm[lr];
            const float* src = xs + lr * QSTRIDE + k0;
#pragma unroll
            for (int j = 0; j < 8; ++j) q[j] = (f16)rintf(src[j] * s);
        }
        *(f16x8*)(outb + (size_t)c * 8) = q;
    }
}

// ---------- per-row weight scale ----------
__global__ void wscale_kernel(const float* __restrict__ w, float* __restrict__ sw) {
    __shared__ float sm[4];
    size_t k = blockIdx.x;
    const float* wr = w + k * (size_t)NF_DIM;
    float m = 0.f;
    const int n4 = NF_DIM >> 2;
    for (int i = threadIdx.x; i < n4; i += blockDim.x) {
        float4 v = ((const float4*)wr)[i];
        m = fmaxf(fmaxf(fmaxf(fabsf(v.x), fabsf(v.y)), fmaxf(fabsf(v.z), fabsf(v.w))), m);
    }
    m = blockMax(m, sm);
    if (threadIdx.x == 0) sw[k] = 127.0f / (m + 1e-6f);
}

// ---------- quantize + transpose weight -> wqt[N][KPAD] fp16 ----------
__global__ void wtq_kernel(const float* __restrict__ w, const float* __restrict__ sw,
                           f16* __restrict__ wqt) {
    __shared__ f16 t[64][80];
    int k0 = blockIdx.x * 64;
    int f0 = blockIdx.y * 64;
    int tid = threadIdx.x;
    if (k0 >= K_DIM) {
        int fr = tid >> 2;
        int ch = (tid & 3) << 4;
        float4 z = {};
        float4* dst = (float4*)&wqt[(size_t)(f0 + fr) * KPAD + k0 + ch];
        dst[0] = z;
        dst[1] = z;
        return;
    }
    int rr = tid >> 4;
    int cc = (tid & 15) << 2;
#pragma unroll
    for (int i = 0; i < 4; ++i) {
        int r = rr + i * 16;
        float s = sw[k0 + r];
        float inv = 1.0f / (s + 1e-6f);
        float4 v = *(const float4*)&w[(size_t)(k0 + r) * NF_DIM + f0 + cc];
        t[cc + 0][r] = (f16)(rintf(v.x * s) * inv);
        t[cc + 1][r] = (f16)(rintf(v.y * s) * inv);
        t[cc + 2][r] = (f16)(rintf(v.z * s) * inv);
        t[cc + 3][r] = (f16)(rintf(v.w * s) * inv);
    }
    __syncthreads();
    int fr = tid >> 2;
    int ch = (tid & 3) << 4;
    const float4* src = (const float4*)&t[fr][ch];
    float4* dst = (float4*)&wqt[(size_t)(f0 + fr) * KPAD + k0 + ch];
    dst[0] = src[0];
    dst[1] = src[1];
}

// ---------- 128x320 GEMM: A direct-from-global (frag-tiled), B via LDS ----------
__global__ __launch_bounds__(512, 1) void gemm_ad(
    const f16* __restrict__ Aq,   // fragment-tiled [M/16][52][64][8]
    const f16* __restrict__ Bt,   // [N][KPAD]
    const float* __restrict__ ax,
    const float* __restrict__ bias,
    float* __restrict__ C, int M, int N) {
    extern __shared__ char lds[];  // two B buffers: [320][64] f16 each

    const int tid = threadIdx.x;
    const int lane = tid & 63;
    const int wv = tid >> 6;   // 0..7
    const int wm = wv >> 2;    // 0..1 (64-row half)
    const int wn = wv & 3;     // 0..3 (80-col quarter)
    const int lr = lane & 15;
    const int lg = lane >> 4;

    const int bid = blockIdx.x;
    const int cpx = gridDim.x >> 3;     // 160 (1280 % 8 == 0 -> bijective)
    const int swz = (bid & 7) * cpx + (bid >> 3);
    const int tm = swz & 63;            // tn-major: consecutive swz share B panel
    const int tn = swz >> 6;
    const size_t m0 = (size_t)tm * 128, n0 = (size_t)tn * 320;

    // ---- B staging (inverse-swizzled source, linear LDS dest) ----
    const int srow8 = lane >> 3;
    const int sslot = (lane & 7) ^ srow8;
    const char* pB = (const char*)Bt + (n0 + (size_t)(wv * 8 + srow8)) * KPB + sslot * 16;
    const int L0 = wv * 1024 + lane * 16;
#define ST_B(bufo, t)                                                          \
    {                                                                          \
        const char* g_ = pB + (size_t)(t) * 128;                               \
        _Pragma("unroll") for (int c_ = 0; c_ < 5; ++c_)                       \
            async_copy16(g_ + (size_t)(c_ * 64) * KPB,                         \
                         lds + (bufo) + c_ * 8192 + L0);                       \
    }

    // ---- A direct loads: 8 frags (4 pieces x 2 kk) per K-step ----
    const f16* aBase = Aq + (size_t)(tm * 8 + wm * 4) * (KB52 * 512) + lane * 8;
#define LD_A(dst, t)                                                           \
    {                                                                          \
        _Pragma("unroll") for (int p_ = 0; p_ < 4; ++p_)                       \
        _Pragma("unroll") for (int kk_ = 0; kk_ < 2; ++kk_)                    \
            dst[p_][kk_] = *(const f16x8*)(aBase +                             \
                (size_t)(p_ * KB52 + 2 * (t) + kk_) * 512);                    \
    }

    // ---- B fragment reads (XOR swizzle folded) ----
    const int bdr0 = (wn * 80 + lr) * 128 + (((lg) ^ (lr & 7)) << 4);
    const int bdr1 = (wn * 80 + lr) * 128 + (((4 + lg) ^ (lr & 7)) << 4);
#define RD_B5(dst, bufo, off)                                                  \
    {                                                                          \
        const char* p_ = lds + (bufo) + (off);                                 \
        _Pragma("unroll") for (int n_ = 0; n_ < 5; ++n_)                       \
            dst[n_] = *(const f16x8*)(p_ + n_ * 2048);                         \
    }

#define BARRIER __builtin_amdgcn_s_barrier()
#define LGKM(n) asm volatile("s_waitcnt lgkmcnt(" #n ")" ::: "memory")
#define VM13 asm volatile("s_waitcnt vmcnt(13)" ::: "memory")
#define SB0 __builtin_amdgcn_sched_barrier(0)

    // 10 MFMA: two A frags x 5 B frags
#define MF10(A0_, A1_, BF, R0)                                                    \
    {                                                                             \
        __builtin_amdgcn_s_setprio(1);                                            \
        _Pragma("unroll") for (int n_ = 0; n_ < 5; ++n_) {                        \
            acc[(R0)][n_] = __builtin_amdgcn_mfma_f32_16x16x32_f16(               \
                A0_, BF[n_], acc[(R0)][n_], 0, 0, 0);                             \
            acc[(R0) + 1][n_] = __builtin_amdgcn_mfma_f32_16x16x32_f16(           \
                A1_, BF[n_], acc[(R0) + 1][n_], 0, 0, 0);                         \
        }                                                                         \
        __builtin_amdgcn_s_setprio(0);                                            \
    }

    // One K-step. ds FIFO (per wave): enter 5 (B0) -> p1 +5 (B1) w(5) ->
    // p2 w(0) -> p4 +5 (B0 next) -> exit 5.
    // vm FIFO: [B(t+1) 5][A(t+1) 8 @p1][B(t+2) 5 @p2] -> VM13 @p4 retires
    // exactly B(t+1) (issued ~2 K-steps earlier). A-frag loads are waited by
    // compiler-inserted counted vmcnt at first MFMA use (1 K-step distance).
#define TILE(CUR, NXT, AC, AN, t1, t2)                                \
    {                                                                 \
        /* p1: A prefetch + B1 read */                                \
        LD_A(AN, t1);                                                 \
        RD_B5(B1, CUR, bdr1);                                         \
        LGKM(5); SB0;                                                 \
        MF10(AC[0][0], AC[1][0], B0, 0);                              \
        /* p2: all CUR.B reads retired -> restage CUR */              \
        LGKM(0); SB0;                                                 \
        BARRIER;                                                      \
        ST_B(CUR, t2); SB0;                                           \
        MF10(AC[2][0], AC[3][0], B0, 2);                              \
        /* p3: pure MFMA */                                           \
        MF10(AC[0][1], AC[1][1], B1, 0);                              \
        /* p4: NXT landed; pre-read next B0 under final MFMA */       \
        VM13; SB0;                                                    \
        BARRIER;                                                      \
        RD_B5(B0, NXT, bdr0); SB0;                                    \
        MF10(AC[2][1], AC[3][1], B1, 2);                              \
    }

    f32x4 acc[4][5] = {};
    f16x8 aC[4][2], aN[4][2], B0[5], B1[5];

    // ---- prologue: B(0)->buf0, B(1)->buf1, A(0)->regs ----
    ST_B(0, 0);
    ST_B(BUFB, 1);
    LD_A(aC, 0);
    VM13;     // retires B(0)'s 5 (outstanding 18 -> 13)
    BARRIER;
    RD_B5(B0, 0, bdr0);   // 5 ds outstanding

    for (int i = 0; i < NKT / 2; ++i) {
        const int t1 = 2 * i + 1;
        const int t2 = (2 * i + 2 < NKT) ? 2 * i + 2 : NKT - 1;
        const int t3 = (2 * i + 3 < NKT) ? 2 * i + 3 : NKT - 1;
        TILE(0, BUFB, aC, aN, t1, t2);
        TILE(BUFB, 0, aN, aC, t2, t3);
    }
    asm volatile("s_waitcnt vmcnt(0) lgkmcnt(0)" ::: "memory");

    // ---- epilogue: direct stores, ax*acc + bias ----
    float bv[5];
#pragma unroll
    for (int n_ = 0; n_ < 5; ++n_) bv[n_] = bias[n0 + wn * 80 + n_ * 16 + lr];
#pragma unroll
    for (int a = 0; a < 4; ++a) {
#pragma unroll
        for (int j = 0; j < 4; ++j) {
            size_t row = m0 + wm * 64 + a * 16 + lg * 4 + j;
            float axv = ax[row];
            float* crow = C + row * (size_t)N + n0 + wn * 80;
#pragma unroll
            for (int n_ = 0; n_ < 5; ++n_)
                crow[n_ * 16 + lr] = acc[a][n_][j] * axv + bv[n_];
        }
    }
}

extern "C" void kernel_launch(void* const* d_in, const int* in_sizes, int n_in,
                              void* d_out, int out_size, void* d_ws, size_t ws_size,
                              hipStream_t stream) {
    const float* x = (const float*)d_in[0];
    const float* w = (const float*)d_in[1];
    const float* bias = (const float*)d_in[2];
    float* out = (float*)d_out;

    const int M = in_sizes[0] / K_DIM;  // 8192
    const int N = NF_DIM;               // 6400

    char* ws = (char*)d_ws;
    f16* qxt = (f16*)ws;                                        // (M/16)*52*512*2 = 27.3MB
    f16* wqt = (f16*)(ws + (size_t)(M / 16) * KB52 * 512 * 2);  // N*KPAD*2
    float* ax = (float*)(ws + (size_t)(M / 16) * KB52 * 512 * 2 + (size_t)N * KPAD * 2);
    float* sw = ax + M;

    (void)hipFuncSetAttribute((const void*)quant_x_kernel,
                              hipFuncAttributeMaxDynamicSharedMemorySize, 16 * QSTRIDE * 4);
    quant_x_kernel<<<M / 16, 256, 16 * QSTRIDE * 4, stream>>>(x, qxt, ax);
    wscale_kernel<<<K_DIM, 256, 0, stream>>>(w, sw);
    wtq_kernel<<<dim3(KPAD / 64, NF_DIM / 64), 256, 0, stream>>>(w, sw, wqt);

    (void)hipFuncSetAttribute((const void*)gemm_ad,
                              hipFuncAttributeMaxDynamicSharedMemorySize, 2 * BUFB);
    gemm_ad<<<(M / 128) * (N / 320), 512, 2 * BUFB, stream>>>(qxt, wqt, ax, bias, out, M, N);
}

// Round 12
// 233.275 us; speedup vs baseline: 1.1490x; 1.1490x over previous
//
#include <hip/hip_runtime.h>
#include <stdint.h>

typedef _Float16 f16;
typedef _Float16 f16x4 __attribute__((ext_vector_type(4)));
typedef _Float16 f16x8 __attribute__((ext_vector_type(8)));
typedef float f32x4 __attribute__((ext_vector_type(4)));

#define K_DIM 1600
#define NF_DIM 6400
#define KPAD 1664   // 26 tiles of 64
#define NKT 26
#define KPB (KPAD * 2)  // row stride bytes = 3328

// GEMM geometry: BM=128, BN=320, BK=64 -> 64x20 = 1280 tiles = 5/CU exact.
// LDS: A dbuf 2x16KB @ {0,16384}; B dbuf 2x40KB @ {32768,73728}. 112KB total.
#define BA0 0
#define BA1 16384
#define BB0 32768
#define BB1 73728
#define LDS_TOTAL 114688

// ---------- async global->LDS 16B copy ----------
__device__ __forceinline__ void async_copy16(const void* g, void* l) {
    __builtin_amdgcn_global_load_lds(
        (const __attribute__((address_space(1))) void*)(uintptr_t)g,
        (__attribute__((address_space(3))) void*)(uint32_t)(uintptr_t)l,
        16, 0, 0);
}

// ---------- block-wide max (256 threads = 4 waves) ----------
__device__ __forceinline__ float blockMax(float v, float* sm) {
#pragma unroll
    for (int off = 32; off > 0; off >>= 1)
        v = fmaxf(v, __shfl_down(v, off, 64));
    int wid = threadIdx.x >> 6, lane = threadIdx.x & 63;
    if (lane == 0) sm[wid] = v;
    __syncthreads();
    if (threadIdx.x == 0) {
        float m = sm[0];
        for (int i = 1; i < (int)(blockDim.x >> 6); ++i) m = fmaxf(m, sm[i]);
        sm[0] = m;
    }
    __syncthreads();
    return sm[0];
}

// ---------- per-token activation quant ----------
__global__ void quant_x_kernel(const float* __restrict__ x, f16* __restrict__ qx,
                               float* __restrict__ ax) {
    __shared__ float sm[4];
    size_t row = blockIdx.x;
    const float* xr = x + row * (size_t)K_DIM;
    float m = 0.f;
    const int n4 = K_DIM >> 2;
    for (int i = threadIdx.x; i < n4; i += blockDim.x) {
        float4 v = ((const float4*)xr)[i];
        m = fmaxf(fmaxf(fmaxf(fabsf(v.x), fabsf(v.y)), fmaxf(fabsf(v.z), fabsf(v.w))), m);
    }
    m = blockMax(m, sm);
    float s = 127.0f / (m + 1e-6f);
    if (threadIdx.x == 0) ax[row] = 1.0f / (s + 1e-6f);
    f16* qr = qx + row * (size_t)KPAD;
    for (int i = threadIdx.x; i < n4; i += blockDim.x) {
        float4 v = ((const float4*)xr)[i];
        f16x4 q;
        q[0] = (f16)rintf(v.x * s);
        q[1] = (f16)rintf(v.y * s);
        q[2] = (f16)rintf(v.z * s);
        q[3] = (f16)rintf(v.w * s);
        *(f16x4*)&qr[i * 4] = q;
    }
    if (threadIdx.x < 16) {
        f16x4 z = {};
        *(f16x4*)&qr[K_DIM + threadIdx.x * 4] = z;
    }
}

// ---------- per-row weight scale ----------
__global__ void wscale_kernel(const float* __restrict__ w, float* __restrict__ sw) {
    __shared__ float sm[4];
    size_t k = blockIdx.x;
    const float* wr = w + k * (size_t)NF_DIM;
    float m = 0.f;
    const int n4 = NF_DIM >> 2;
    for (int i = threadIdx.x; i < n4; i += blockDim.x) {
        float4 v = ((const float4*)wr)[i];
        m = fmaxf(fmaxf(fmaxf(fabsf(v.x), fabsf(v.y)), fmaxf(fabsf(v.z), fabsf(v.w))), m);
    }
    m = blockMax(m, sm);
    if (threadIdx.x == 0) sw[k] = 127.0f / (m + 1e-6f);
}

// ---------- quantize + transpose weight -> wqt[N][KPAD] fp16 ----------
__global__ void wtq_kernel(const float* __restrict__ w, const float* __restrict__ sw,
                           f16* __restrict__ wqt) {
    __shared__ f16 t[64][80];
    int k0 = blockIdx.x * 64;
    int f0 = blockIdx.y * 64;
    int tid = threadIdx.x;
    if (k0 >= K_DIM) {
        int fr = tid >> 2;
        int ch = (tid & 3) << 4;
        float4 z = {};
        float4* dst = (float4*)&wqt[(size_t)(f0 + fr) * KPAD + k0 + ch];
        dst[0] = z;
        dst[1] = z;
        return;
    }
    int rr = tid >> 4;
    int cc = (tid & 15) << 2;
#pragma unroll
    for (int i = 0; i < 4; ++i) {
        int r = rr + i * 16;
        float s = sw[k0 + r];
        float inv = 1.0f / (s + 1e-6f);
        float4 v = *(const float4*)&w[(size_t)(k0 + r) * NF_DIM + f0 + cc];
        t[cc + 0][r] = (f16)(rintf(v.x * s) * inv);
        t[cc + 1][r] = (f16)(rintf(v.y * s) * inv);
        t[cc + 2][r] = (f16)(rintf(v.z * s) * inv);
        t[cc + 3][r] = (f16)(rintf(v.w * s) * inv);
    }
    __syncthreads();
    int fr = tid >> 2;
    int ch = (tid & 3) << 4;
    const float4* src = (const float4*)&t[fr][ch];
    float4* dst = (float4*)&wqt[(size_t)(f0 + fr) * KPAD + k0 + ch];
    dst[0] = src[0];
    dst[1] = src[1];
}

// ---------- 128x320 GEMM: m201 rhythm (read -> BAR -> lgkm(0) -> MFMA -> BAR) ----------
__global__ __launch_bounds__(512, 1) void gemm128x320(
    const f16* __restrict__ A,    // [M][KPAD]
    const f16* __restrict__ Bt,   // [N][KPAD]
    const float* __restrict__ ax,
    const float* __restrict__ bias,
    float* __restrict__ C, int M, int N) {
    extern __shared__ char lds[];

    const int tid = threadIdx.x;
    const int lane = tid & 63;
    const int wv = tid >> 6;   // 0..7
    const int wm = wv >> 2;    // 0..1 (64-row half)
    const int wn = wv & 3;     // 0..3 (80-col quarter)
    const int lr = lane & 15;
    const int lg = lane >> 4;

    const int bid = blockIdx.x;
    const int cpx = gridDim.x >> 3;     // 160 (1280 % 8 == 0 -> bijective)
    const int swz = (bid & 7) * cpx + (bid >> 3);
    const int tm = swz & 63;            // tn-major: consecutive swz share B panel
    const int tn = swz >> 6;
    const size_t m0 = (size_t)tm * 128, n0 = (size_t)tn * 320;

    // ---- staging pointers (inverse-swizzled source, linear LDS dest) ----
    const int srow8 = lane >> 3;
    const int sslot = (lane & 7) ^ srow8;
    const char* pA = (const char*)A + (m0 + (size_t)(wv * 8 + srow8)) * KPB + sslot * 16;
    const char* pB = (const char*)Bt + (n0 + (size_t)(wv * 8 + srow8)) * KPB + sslot * 16;
    const int L0 = wv * 1024 + lane * 16;

    // A tile 128x64: 2 loads/thread; B tile 320x64: 5 loads/thread
#define ST_A(bufo, t)                                                          \
    {                                                                          \
        const char* g_ = pA + (size_t)(t) * 128;                               \
        async_copy16(g_, lds + (bufo) + L0);                                   \
        async_copy16(g_ + (size_t)64 * KPB, lds + (bufo) + 8192 + L0);         \
    }
#define ST_B(bufo, t)                                                          \
    {                                                                          \
        const char* g_ = pB + (size_t)(t) * 128;                               \
        _Pragma("unroll") for (int c_ = 0; c_ < 5; ++c_)                       \
            async_copy16(g_ + (size_t)(c_ * 64) * KPB,                         \
                         lds + (bufo) + c_ * 8192 + L0);                       \
    }

    // ---- fragment-read constants (XOR swizzle folded per-thread) ----
    const int swz0 = ((lg) ^ (lr & 7)) << 4;       // kk=0 chunk
    const int swz1 = ((4 + lg) ^ (lr & 7)) << 4;   // kk=1 chunk
    const int rbA = (wm * 64 + lr) * 128;          // within A buffer
    const int rbB = (wn * 80 + lr) * 128;          // within B buffer

    // A piece: 2 frags (rows +0,+16); rowoff 0 = rows 0-31 of wave half, 4096 = 32-63
#define RD_A(dst, bufo, rowoff, sz)                                    \
    {                                                                  \
        const char* p_ = lds + (bufo) + rbA + (rowoff) + (sz);         \
        dst[0] = *(const f16x8*)(p_);                                  \
        dst[1] = *(const f16x8*)(p_ + 2048);                           \
    }
    // B set of one kk: 5 frags
#define RD_B5(dst, bufo, sz)                                           \
    {                                                                  \
        const char* p_ = lds + (bufo) + rbB + (sz);                    \
        _Pragma("unroll") for (int n_ = 0; n_ < 5; ++n_)               \
            dst[n_] = *(const f16x8*)(p_ + n_ * 2048);                 \
    }

#define BARRIER __builtin_amdgcn_s_barrier()
#define LGKM0 asm volatile("s_waitcnt lgkmcnt(0)" ::: "memory")
#define VM5 asm volatile("s_waitcnt vmcnt(5)" ::: "memory")
#define SB0 __builtin_amdgcn_sched_barrier(0)

    // 10 MFMA: A piece (2 frags) x 5 B frags
#define MF10(AF, BF, R0)                                                          \
    {                                                                             \
        __builtin_amdgcn_s_setprio(1);                                            \
        _Pragma("unroll") for (int a_ = 0; a_ < 2; ++a_)                          \
        _Pragma("unroll") for (int n_ = 0; n_ < 5; ++n_)                          \
            acc[(R0) + a_][n_] = __builtin_amdgcn_mfma_f32_16x16x32_f16(          \
                AF[a_], BF[n_], acc[(R0) + a_][n_], 0, 0, 0);                     \
        __builtin_amdgcn_s_setprio(0);                                            \
    }

    // One K-tile, m201 rhythm. Per phase: {reads ∥ staging} -> BAR -> lgkm(0)
    // -> SB0 -> 10 MFMA -> BAR. vm FIFO: enter [Bst(t+1) 5]; ph1 +2 Ast(t+1);
    // ph4 +5 Bst(t+2) then VM5 retires Bst(t+1)+Ast(t+1), leaves [Bst(t+2) 5].
    // ST_B at ph4 targets this tile's own B buffer: all its reads retired by
    // ph3's per-wave LGKM0, sealed by ph3's closing barrier.
#define TILE(bA, bAn, bB, tA, tB)                                     \
    {                                                                 \
        /* ph1 */                                                     \
        RD_A(aF, bA, 0, swz0);                                        \
        RD_B5(Bf, bB, swz0);                                          \
        ST_A(bAn, tA);                                                \
        BARRIER; LGKM0; SB0;                                          \
        MF10(aF, Bf, 0);                                              \
        BARRIER;                                                      \
        /* ph2 */                                                     \
        RD_A(aG, bA, 4096, swz0);                                     \
        BARRIER; LGKM0; SB0;                                          \
        MF10(aG, Bf, 2);                                              \
        BARRIER;                                                      \
        /* ph3 */                                                     \
        RD_A(aF, bA, 0, swz1);                                        \
        RD_B5(Bg, bB, swz1);                                          \
        BARRIER; LGKM0; SB0;                                          \
        MF10(aF, Bg, 0);                                              \
        BARRIER;                                                      \
        /* ph4 */                                                     \
        RD_A(aG, bA, 4096, swz1);                                     \
        ST_B(bB, tB);                                                 \
        VM5;                                                          \
        BARRIER; LGKM0; SB0;                                          \
        MF10(aG, Bg, 2);                                              \
        BARRIER;                                                      \
    }

    f32x4 acc[4][5] = {};
    f16x8 aF[2], aG[2], Bf[5], Bg[5];

    // ---- prologue: A(0), B(0), B(1); counted wait leaves Bst(1) in flight ----
    ST_A(BA0, 0);
    ST_B(BB0, 0);
    ST_B(BB1, 1);
    VM5;      // retires A(0)+B(0); Bst(1) 5 outstanding (steady-state invariant)
    BARRIER;

    for (int i = 0; i < NKT / 2; ++i) {
        const int te = 2 * i + 1;                                // A-stage idx, even tile
        const int tb2 = (2 * i + 2 < NKT) ? 2 * i + 2 : NKT - 1; // clamped dead-writes
        const int tb3 = (2 * i + 3 < NKT) ? 2 * i + 3 : NKT - 1;
        TILE(BA0, BA1, BB0, te, tb2);
        TILE(BA1, BA0, BB1, tb2, tb3);
    }
    asm volatile("s_waitcnt vmcnt(0) lgkmcnt(0)" ::: "memory");

    // ---- epilogue: direct stores, ax*acc + bias ----
    float bv[5];
#pragma unroll
    for (int n_ = 0; n_ < 5; ++n_) bv[n_] = bias[n0 + wn * 80 + n_ * 16 + lr];
#pragma unroll
    for (int a = 0; a < 4; ++a) {
#pragma unroll
        for (int j = 0; j < 4; ++j) {
            size_t row = m0 + wm * 64 + a * 16 + lg * 4 + j;
            float axv = ax[row];
            float* crow = C + row * (size_t)N + n0 + wn * 80;
#pragma unroll
            for (int n_ = 0; n_ < 5; ++n_)
                crow[n_ * 16 + lr] = acc[a][n_][j] * axv + bv[n_];
        }
    }
}

extern "C" void kernel_launch(void* const* d_in, const int* in_sizes, int n_in,
                              void* d_out, int out_size, void* d_ws, size_t ws_size,
                              hipStream_t stream) {
    const float* x = (const float*)d_in[0];
    const float* w = (const float*)d_in[1];
    const float* bias = (const float*)d_in[2];
    float* out = (float*)d_out;

    const int M = in_sizes[0] / K_DIM;  // 8192
    const int N = NF_DIM;               // 6400

    char* ws = (char*)d_ws;
    f16* qx = (f16*)ws;
    f16* wqt = (f16*)(ws + (size_t)M * KPAD * 2);
    float* ax = (float*)(ws + (size_t)M * KPAD * 2 + (size_t)N * KPAD * 2);
    float* sw = ax + M;

    quant_x_kernel<<<M, 256, 0, stream>>>(x, qx, ax);
    wscale_kernel<<<K_DIM, 256, 0, stream>>>(w, sw);
    wtq_kernel<<<dim3(KPAD / 64, NF_DIM / 64), 256, 0, stream>>>(w, sw, wqt);

    (void)hipFuncSetAttribute((const void*)gemm128x320,
                              hipFuncAttributeMaxDynamicSharedMemorySize, LDS_TOTAL);
    gemm128x320<<<(M / 128) * (N / 320), 512, LDS_TOTAL, stream>>>(qx, wqt, ax, bias, out, M, N);
}

// Round 13
// 233.240 us; speedup vs baseline: 1.1492x; 1.0001x over previous
//
#include <hip/hip_runtime.h>
#include <stdint.h>

typedef _Float16 f16;
typedef _Float16 f16x4 __attribute__((ext_vector_type(4)));
typedef _Float16 f16x8 __attribute__((ext_vector_type(8)));
typedef float f32x4 __attribute__((ext_vector_type(4)));

#define K_DIM 1600
#define NF_DIM 6400
#define KPAD 1664   // 26 tiles of 64
#define NKT 26
#define KPB (KPAD * 2)  // row stride bytes = 3328

// GEMM geometry: BM=128, BN=320, BK=64 -> 64x20 = 1280 tiles = 5/CU exact.
// LDS: A dbuf 2x16KB @ {0,16384}; B dbuf 2x40KB @ {32768,73728}. 112KB total.
#define BA0 0
#define BA1 16384
#define BB0 32768
#define BB1 73728
#define LDS_TOTAL 114688

// ---------- async global->LDS 16B copy ----------
__device__ __forceinline__ void async_copy16(const void* g, void* l) {
    __builtin_amdgcn_global_load_lds(
        (const __attribute__((address_space(1))) void*)(uintptr_t)g,
        (__attribute__((address_space(3))) void*)(uint32_t)(uintptr_t)l,
        16, 0, 0);
}

// ---------- block-wide max (256 threads = 4 waves) ----------
__device__ __forceinline__ float blockMax(float v, float* sm) {
#pragma unroll
    for (int off = 32; off > 0; off >>= 1)
        v = fmaxf(v, __shfl_down(v, off, 64));
    int wid = threadIdx.x >> 6, lane = threadIdx.x & 63;
    if (lane == 0) sm[wid] = v;
    __syncthreads();
    if (threadIdx.x == 0) {
        float m = sm[0];
        for (int i = 1; i < (int)(blockDim.x >> 6); ++i) m = fmaxf(m, sm[i]);
        sm[0] = m;
    }
    __syncthreads();
    return sm[0];
}

// ---------- per-token activation quant ----------
__global__ void quant_x_kernel(const float* __restrict__ x, f16* __restrict__ qx,
                               float* __restrict__ ax) {
    __shared__ float sm[4];
    size_t row = blockIdx.x;
    const float* xr = x + row * (size_t)K_DIM;
    float m = 0.f;
    const int n4 = K_DIM >> 2;
    for (int i = threadIdx.x; i < n4; i += blockDim.x) {
        float4 v = ((const float4*)xr)[i];
        m = fmaxf(fmaxf(fmaxf(fabsf(v.x), fabsf(v.y)), fmaxf(fabsf(v.z), fabsf(v.w))), m);
    }
    m = blockMax(m, sm);
    float s = 127.0f / (m + 1e-6f);
    if (threadIdx.x == 0) ax[row] = 1.0f / (s + 1e-6f);
    f16* qr = qx + row * (size_t)KPAD;
    for (int i = threadIdx.x; i < n4; i += blockDim.x) {
        float4 v = ((const float4*)xr)[i];
        f16x4 q;
        q[0] = (f16)rintf(v.x * s);
        q[1] = (f16)rintf(v.y * s);
        q[2] = (f16)rintf(v.z * s);
        q[3] = (f16)rintf(v.w * s);
        *(f16x4*)&qr[i * 4] = q;
    }
    if (threadIdx.x < 16) {
        f16x4 z = {};
        *(f16x4*)&qr[K_DIM + threadIdx.x * 4] = z;
    }
}

// ---------- per-row weight scale ----------
__global__ void wscale_kernel(const float* __restrict__ w, float* __restrict__ sw) {
    __shared__ float sm[4];
    size_t k = blockIdx.x;
    const float* wr = w + k * (size_t)NF_DIM;
    float m = 0.f;
    const int n4 = NF_DIM >> 2;
    for (int i = threadIdx.x; i < n4; i += blockDim.x) {
        float4 v = ((const float4*)wr)[i];
        m = fmaxf(fmaxf(fmaxf(fabsf(v.x), fabsf(v.y)), fmaxf(fabsf(v.z), fabsf(v.w))), m);
    }
    m = blockMax(m, sm);
    if (threadIdx.x == 0) sw[k] = 127.0f / (m + 1e-6f);
}

// ---------- quantize + transpose weight -> wqt[N][KPAD] fp16 ----------
__global__ void wtq_kernel(const float* __restrict__ w, const float* __restrict__ sw,
                           f16* __restrict__ wqt) {
    __shared__ f16 t[64][80];
    int k0 = blockIdx.x * 64;
    int f0 = blockIdx.y * 64;
    int tid = threadIdx.x;
    if (k0 >= K_DIM) {
        int fr = tid >> 2;
        int ch = (tid & 3) << 4;
        float4 z = {};
        float4* dst = (float4*)&wqt[(size_t)(f0 + fr) * KPAD + k0 + ch];
        dst[0] = z;
        dst[1] = z;
        return;
    }
    int rr = tid >> 4;
    int cc = (tid & 15) << 2;
#pragma unroll
    for (int i = 0; i < 4; ++i) {
        int r = rr + i * 16;
        float s = sw[k0 + r];
        float inv = 1.0f / (s + 1e-6f);
        float4 v = *(const float4*)&w[(size_t)(k0 + r) * NF_DIM + f0 + cc];
        t[cc + 0][r] = (f16)(rintf(v.x * s) * inv);
        t[cc + 1][r] = (f16)(rintf(v.y * s) * inv);
        t[cc + 2][r] = (f16)(rintf(v.z * s) * inv);
        t[cc + 3][r] = (f16)(rintf(v.w * s) * inv);
    }
    __syncthreads();
    int fr = tid >> 2;
    int ch = (tid & 3) << 4;
    const float4* src = (const float4*)&t[fr][ch];
    float4* dst = (float4*)&wqt[(size_t)(f0 + fr) * KPAD + k0 + ch];
    dst[0] = src[0];
    dst[1] = src[1];
}

// ---------- 128x320 GEMM: m201 rhythm (read -> BAR -> lgkm(0) -> MFMA -> BAR) ----------
__global__ __launch_bounds__(512, 1) void gemm128x320(
    const f16* __restrict__ A,    // [M][KPAD]
    const f16* __restrict__ Bt,   // [N][KPAD]
    const float* __restrict__ ax,
    const float* __restrict__ bias,
    float* __restrict__ C, int M, int N) {
    extern __shared__ char lds[];

    const int tid = threadIdx.x;
    const int lane = tid & 63;
    const int wv = tid >> 6;   // 0..7
    const int wm = wv >> 2;    // 0..1 (64-row half)
    const int wn = wv & 3;     // 0..3 (80-col quarter)
    const int lr = lane & 15;
    const int lg = lane >> 4;

    const int bid = blockIdx.x;
    const int cpx = gridDim.x >> 3;     // 160 (1280 % 8 == 0 -> bijective)
    const int swz = (bid & 7) * cpx + (bid >> 3);
    const int tm = swz & 63;            // tn-major: consecutive swz share B panel
    const int tn = swz >> 6;
    const size_t m0 = (size_t)tm * 128, n0 = (size_t)tn * 320;

    // ---- staging pointers (inverse-swizzled source, linear LDS dest) ----
    const int srow8 = lane >> 3;
    const int sslot = (lane & 7) ^ srow8;
    const char* pA = (const char*)A + (m0 + (size_t)(wv * 8 + srow8)) * KPB + sslot * 16;
    const char* pB = (const char*)Bt + (n0 + (size_t)(wv * 8 + srow8)) * KPB + sslot * 16;
    const int L0 = wv * 1024 + lane * 16;

    // A tile 128x64: 2 loads/thread; B tile 320x64: 5 loads/thread
#define ST_A(bufo, t)                                                          \
    {                                                                          \
        const char* g_ = pA + (size_t)(t) * 128;                               \
        async_copy16(g_, lds + (bufo) + L0);                                   \
        async_copy16(g_ + (size_t)64 * KPB, lds + (bufo) + 8192 + L0);         \
    }
#define ST_B(bufo, t)                                                          \
    {                                                                          \
        const char* g_ = pB + (size_t)(t) * 128;                               \
        _Pragma("unroll") for (int c_ = 0; c_ < 5; ++c_)                       \
            async_copy16(g_ + (size_t)(c_ * 64) * KPB,                         \
                         lds + (bufo) + c_ * 8192 + L0);                       \
    }

    // ---- fragment-read constants (XOR swizzle folded per-thread) ----
    const int swz0 = ((lg) ^ (lr & 7)) << 4;       // kk=0 chunk
    const int swz1 = ((4 + lg) ^ (lr & 7)) << 4;   // kk=1 chunk
    const int rbA = (wm * 64 + lr) * 128;          // within A buffer
    const int rbB = (wn * 80 + lr) * 128;          // within B buffer

    // A piece: 2 frags (rows +0,+16); rowoff 0 = rows 0-31 of wave half, 4096 = 32-63
#define RD_A(dst, bufo, rowoff, sz)                                    \
    {                                                                  \
        const char* p_ = lds + (bufo) + rbA + (rowoff) + (sz);         \
        dst[0] = *(const f16x8*)(p_);                                  \
        dst[1] = *(const f16x8*)(p_ + 2048);                           \
    }
    // B set of one kk: 5 frags
#define RD_B5(dst, bufo, sz)                                           \
    {                                                                  \
        const char* p_ = lds + (bufo) + rbB + (sz);                    \
        _Pragma("unroll") for (int n_ = 0; n_ < 5; ++n_)               \
            dst[n_] = *(const f16x8*)(p_ + n_ * 2048);                 \
    }

#define BARRIER __builtin_amdgcn_s_barrier()
#define LGKM0 asm volatile("s_waitcnt lgkmcnt(0)" ::: "memory")
#define VM5 asm volatile("s_waitcnt vmcnt(5)" ::: "memory")
#define SB0 __builtin_amdgcn_sched_barrier(0)

    // 10 MFMA: A piece (2 frags) x 5 B frags
#define MF10(AF, BF, R0)                                                          \
    {                                                                             \
        __builtin_amdgcn_s_setprio(1);                                            \
        _Pragma("unroll") for (int a_ = 0; a_ < 2; ++a_)                          \
        _Pragma("unroll") for (int n_ = 0; n_ < 5; ++n_)                          \
            acc[(R0) + a_][n_] = __builtin_amdgcn_mfma_f32_16x16x32_f16(          \
                AF[a_], BF[n_], acc[(R0) + a_][n_], 0, 0, 0);                     \
        __builtin_amdgcn_s_setprio(0);                                            \
    }

    // One K-tile, m201 rhythm. Per phase: {reads ∥ staging} -> BAR -> lgkm(0)
    // -> SB0 -> 10 MFMA -> BAR. vm FIFO: enter [Bst(t+1) 5]; ph1 +2 Ast(t+1);
    // ph4 +5 Bst(t+2) then VM5 retires Bst(t+1)+Ast(t+1), leaves [Bst(t+2) 5].
    // ST_B at ph4 targets this tile's own B buffer: all its reads retired by
    // ph3's per-wave LGKM0, sealed by ph3's closing barrier.
#define TILE(bA, bAn, bB, tA, tB)                                     \
    {                                                                 \
        /* ph1 */                                                     \
        RD_A(aF, bA, 0, swz0);                                        \
        RD_B5(Bf, bB, swz0);                                          \
        ST_A(bAn, tA);                                                \
        BARRIER; LGKM0; SB0;                                          \
        MF10(aF, Bf, 0);                                              \
        BARRIER;                                                      \
        /* ph2 */                                                     \
        RD_A(aG, bA, 4096, swz0);                                     \
        BARRIER; LGKM0; SB0;                                          \
        MF10(aG, Bf, 2);                                              \
        BARRIER;                                                      \
        /* ph3 */                                                     \
        RD_A(aF, bA, 0, swz1);                                        \
        RD_B5(Bg, bB, swz1);                                          \
        BARRIER; LGKM0; SB0;                                          \
        MF10(aF, Bg, 0);                                              \
        BARRIER;                                                      \
        /* ph4 */                                                     \
        RD_A(aG, bA, 4096, swz1);                                     \
        ST_B(bB, tB);                                                 \
        VM5;                                                          \
        BARRIER; LGKM0; SB0;                                          \
        MF10(aG, Bg, 2);                                              \
        BARRIER;                                                      \
    }

    f32x4 acc[4][5] = {};
    f16x8 aF[2], aG[2], Bf[5], Bg[5];

    // ---- prologue: A(0), B(0), B(1); counted wait leaves Bst(1) in flight ----
    ST_A(BA0, 0);
    ST_B(BB0, 0);
    ST_B(BB1, 1);
    VM5;      // retires A(0)+B(0); Bst(1) 5 outstanding (steady-state invariant)
    BARRIER;

    for (int i = 0; i < NKT / 2; ++i) {
        const int te = 2 * i + 1;                                // A-stage idx, even tile
        const int tb2 = (2 * i + 2 < NKT) ? 2 * i + 2 : NKT - 1; // clamped dead-writes
        const int tb3 = (2 * i + 3 < NKT) ? 2 * i + 3 : NKT - 1;
        TILE(BA0, BA1, BB0, te, tb2);
        TILE(BA1, BA0, BB1, tb2, tb3);
    }
    asm volatile("s_waitcnt vmcnt(0) lgkmcnt(0)" ::: "memory");

    // ---- epilogue: direct stores, ax*acc + bias ----
    float bv[5];
#pragma unroll
    for (int n_ = 0; n_ < 5; ++n_) bv[n_] = bias[n0 + wn * 80 + n_ * 16 + lr];
#pragma unroll
    for (int a = 0; a < 4; ++a) {
#pragma unroll
        for (int j = 0; j < 4; ++j) {
            size_t row = m0 + wm * 64 + a * 16 + lg * 4 + j;
            float axv = ax[row];
            float* crow = C + row * (size_t)N + n0 + wn * 80;
#pragma unroll
            for (int n_ = 0; n_ < 5; ++n_)
                crow[n_ * 16 + lr] = acc[a][n_][j] * axv + bv[n_];
        }
    }
}

extern "C" void kernel_launch(void* const* d_in, const int* in_sizes, int n_in,
                              void* d_out, int out_size, void* d_ws, size_t ws_size,
                              hipStream_t stream) {
    const float* x = (const float*)d_in[0];
    const float* w = (const float*)d_in[1];
    const float* bias = (const float*)d_in[2];
    float* out = (float*)d_out;

    const int M = in_sizes[0] / K_DIM;  // 8192
    const int N = NF_DIM;               // 6400

    char* ws = (char*)d_ws;
    f16* qx = (f16*)ws;
    f16* wqt = (f16*)(ws + (size_t)M * KPAD * 2);
    float* ax = (float*)(ws + (size_t)M * KPAD * 2 + (size_t)N * KPAD * 2);
    float* sw = ax + M;

    quant_x_kernel<<<M, 256, 0, stream>>>(x, qx, ax);
    wscale_kernel<<<K_DIM, 256, 0, stream>>>(w, sw);
    wtq_kernel<<<dim3(KPAD / 64, NF_DIM / 64), 256, 0, stream>>>(w, sw, wqt);

    (void)hipFuncSetAttribute((const void*)gemm128x320,
                              hipFuncAttributeMaxDynamicSharedMemorySize, LDS_TOTAL);
    gemm128x320<<<(M / 128) * (N / 320), 512, LDS_TOTAL, stream>>>(qx, wqt, ax, bias, out, M, N);
}